// Round 3
// baseline (106.330 us; speedup 1.0000x reference)
//
#include <hip/hip_runtime.h>
#include <stdint.h>

#define HW 65536   // 256*256
#define C_ 64

typedef __attribute__((ext_vector_type(8))) short short8;
typedef __attribute__((ext_vector_type(4))) float f32x4;

#define MFMA(a, b, c) __builtin_amdgcn_mfma_f32_16x16x32_bf16((a), (b), (c), 0, 0, 0)

union U16x8 { uint4 q; short8 v; uint32_t u[4]; };

__device__ inline uint32_t pack_bf16(float lo, float hi) {
  uint32_t ul = __float_as_uint(lo), uh = __float_as_uint(hi);
  ul = (ul + 0x7fffu + ((ul >> 16) & 1u)) >> 16;
  uh = (uh + 0x7fffu + ((uh >> 16) & 1u)) >> 16;
  return ul | (uh << 16);
}
__device__ inline uint16_t bf16r(float f) {
  uint32_t u = __float_as_uint(f);
  return (uint16_t)((u + 0x7fffu + ((u >> 16) & 1u)) >> 16);
}
__device__ inline short8 ld8(const uint16_t* p) {
  U16x8 t; t.q = *(const uint4*)p; return t.v;
}
// [pixel][64 c] bf16 tile, XOR swizzle (16B granule): 2-way max on b128 reads
__device__ inline int pc_idx(int pixel, int c) {
  return (pixel * 64 + c) ^ ((pixel & 7) << 3);
}
// [c][256 j] bf16 tile (V layout)
__device__ inline int cj_idx(int c, int j) {
  return (c * 256 + j) ^ ((c & 7) << 3);
}

__global__ __launch_bounds__(1024, 4) void SCAM_73151882985874_kernel(
    const float* __restrict__ x, const float* __restrict__ res_enc,
    const float* __restrict__ tr_feat,
    const float* __restrict__ Wl1, const float* __restrict__ bl1,
    const float* __restrict__ Wr1, const float* __restrict__ br1,
    const float* __restrict__ Wl2, const float* __restrict__ bl2,
    const float* __restrict__ Wr2, const float* __restrict__ br2,
    const float* __restrict__ beta1, const float* __restrict__ gamma1,
    const float* __restrict__ beta3, const float* __restrict__ gamma3,
    float* __restrict__ out)
{
  __shared__ uint16_t R1[16384];   // xl -> Q*0.125 (in-place)   [pixel][c]
  __shared__ uint16_t R2[16384];   // xr -> S       (in-place)   [pixel][c]
  __shared__ uint16_t R3[16384];   // bufL   [c][j]
  __shared__ uint16_t R4[16384];   // bufR   [c][j]
  __shared__ uint16_t sP[10240];   // per-wave P: 16 x [16][40]

  const int tid = threadIdx.x;
  const int wid = tid >> 6, lane = tid & 63, g = lane >> 4, li = lane & 15;
  const int bb = blockIdx.x >> 8, hh = blockIdx.x & 255;
  const float yy = (float)hh * (2.0f / 255.0f) - 1.0f;
  const float rr = fabsf(yy - 0.5f);

  const size_t rowoff = (size_t)hh * 256;
  const float* xl  = x + ((size_t)bb * C_) * HW + rowoff;
  const float* xr  = x + ((size_t)(2 + bb) * C_) * HW + rowoff;
  const float* trl = tr_feat + ((size_t)bb * C_) * HW + rowoff;
  const float* trr = tr_feat + ((size_t)(2 + bb) * C_) * HW + rowoff;
  const float* rel = res_enc + ((size_t)bb * C_) * HW + rowoff;
  const float* rer = res_enc + ((size_t)(2 + bb) * C_) * HW + rowoff;
  float* outL = out + ((size_t)bb * C_) * HW + rowoff;
  float* outR = out + ((size_t)(2 + bb) * C_) * HW + rowoff;

  // ---------- Phase A: stage xl -> R1, xr -> R2 (f32 -> bf16 [pixel][c]) ----------
  {
    const int side = tid >> 9;       // 0: left, 1: right
    const int t    = tid & 511;
    const int p    = t & 255, h2 = t >> 8;   // h2 in 0..1
    const float* src = side ? xr : xl;
    uint16_t* dst = side ? R2 : R1;
    #pragma unroll
    for (int cb = 0; cb < 4; ++cb) {
      int c0 = h2 * 32 + cb * 8;
      const float* s = src + (size_t)c0 * HW + p;
      U16x8 t8;
      t8.u[0] = pack_bf16(s[0],              s[(size_t)HW]);
      t8.u[1] = pack_bf16(s[2 * (size_t)HW], s[3 * (size_t)HW]);
      t8.u[2] = pack_bf16(s[4 * (size_t)HW], s[5 * (size_t)HW]);
      t8.u[3] = pack_bf16(s[6 * (size_t)HW], s[7 * (size_t)HW]);
      *(uint4*)&dst[pc_idx(p, c0)] = t8.q;
    }
  }
  __syncthreads();

  const int pix = wid * 16 + li;

  // x fragments into registers BEFORE any in-place overwrite
  short8 bxL0 = ld8(&R1[pc_idx(pix, g * 8)]);
  short8 bxL1 = ld8(&R1[pc_idx(pix, 32 + g * 8)]);
  short8 bxR0 = ld8(&R2[pc_idx(pix, g * 8)]);
  short8 bxR1 = ld8(&R2[pc_idx(pix, 32 + g * 8)]);

  // ---------- Phase B: all four 1x1 convs (MFMA), one barrier ----------
  auto conv_one = [&](const float* __restrict__ Wm, int ldw,
                      const float* __restrict__ bias, const float* __restrict__ mod,
                      const float* __restrict__ E, int coord, float qscale,
                      short8 bx0, short8 bx1,
                      uint16_t* dstPC, uint16_t* dstV) {
    #pragma unroll
    for (int ct = 0; ct < 4; ++ct) {
      // prefetch E + effective bias for this ct
      float ev[4], be[4];
      #pragma unroll
      for (int r = 0; r < 4; ++r) {
        int c = ct * 16 + 4 * g + r;
        ev[r] = E[(size_t)c * HW + pix];
        float b = bias[c] + mod[c] * 0.0f;
        if (coord) b += Wm[(size_t)c * ldw + 64] * yy + Wm[(size_t)c * ldw + 65] * rr;
        be[r] = b;
      }
      float md[4];
      #pragma unroll
      for (int r = 0; r < 4; ++r) md[r] = mod[ct * 16 + 4 * g + r];
      // W fragments (A operand): rows = c_out, k = c_in
      short8 af0, af1;
      {
        const float* wr = Wm + (size_t)(ct * 16 + li) * ldw + g * 8;
        U16x8 t8;
        t8.u[0] = pack_bf16(wr[0], wr[1]); t8.u[1] = pack_bf16(wr[2], wr[3]);
        t8.u[2] = pack_bf16(wr[4], wr[5]); t8.u[3] = pack_bf16(wr[6], wr[7]);
        af0 = t8.v;
        const float* wr2 = wr + 32;
        t8.u[0] = pack_bf16(wr2[0], wr2[1]); t8.u[1] = pack_bf16(wr2[2], wr2[3]);
        t8.u[2] = pack_bf16(wr2[4], wr2[5]); t8.u[3] = pack_bf16(wr2[6], wr2[7]);
        af1 = t8.v;
      }
      f32x4 acc = {0.f, 0.f, 0.f, 0.f};
      acc = MFMA(af0, bx0, acc);
      acc = MFMA(af1, bx1, acc);
      uint16_t pk[4];
      #pragma unroll
      for (int r = 0; r < 4; ++r)
        pk[r] = bf16r((acc[r] + be[r] + md[r] * ev[r]) * qscale);
      if (dstV) {
        #pragma unroll
        for (int r = 0; r < 4; ++r) dstV[cj_idx(ct * 16 + 4 * g + r, pix)] = pk[r];
      } else {
        uint2 w2;
        w2.x = (uint32_t)pk[0] | ((uint32_t)pk[1] << 16);
        w2.y = (uint32_t)pk[2] | ((uint32_t)pk[3] << 16);
        *(uint2*)&dstPC[pc_idx(pix, ct * 16 + 4 * g)] = w2;
      }
    }
  };

  conv_one(Wl1, 66, bl1, beta1, trl, 1, 0.125f, bxL0, bxL1, R1, nullptr);  // Q (scaled)
  conv_one(Wr1, 66, br1, beta1, trr, 1, 1.0f,   bxR0, bxR1, R2, nullptr);  // S
  conv_one(Wl2, 64, bl2, gamma1, rel, 0, 1.0f,  bxL0, bxL1, nullptr, R3);  // bufL
  conv_one(Wr2, 64, br2, gamma1, rer, 0, 1.0f,  bxR0, bxR1, nullptr, R4);  // bufR
  __syncthreads();

  uint16_t* Pw = &sP[wid * 640];
  const int h = wid >> 1;

  // ---------- pass 2: out_R column tile = own pixels; sum over a >= own ----------
  {
    short8 bS0 = ld8(&R2[pc_idx(pix, g * 8)]);
    short8 bS1 = ld8(&R2[pc_idx(pix, 32 + g * 8)]);
    f32x4 acc[4] = {{0,0,0,0},{0,0,0,0},{0,0,0,0},{0,0,0,0}};
    float z = 0.f;
    for (int ip = h; ip < 8; ++ip) {
      #pragma unroll
      for (int itl = 0; itl < 2; ++itl) {
        int arow = ip * 32 + itl * 16 + li;
        short8 aQ0 = ld8(&R1[pc_idx(arow, g * 8)]);
        short8 aQ1 = ld8(&R1[pc_idx(arow, 32 + g * 8)]);
        f32x4 s = {0.f, 0.f, 0.f, 0.f};
        s = MFMA(aQ0, bS0, s);
        s = MFMA(aQ1, bS1, s);
        uint16_t pk[4];
        #pragma unroll
        for (int r = 0; r < 4; ++r) {
          int aidx = ip * 32 + itl * 16 + 4 * g + r;
          float p = (aidx >= pix) ? __expf(s[r]) : 0.f;
          z += p; pk[r] = bf16r(p);
        }
        uint2 w2;
        w2.x = (uint32_t)pk[0] | ((uint32_t)pk[1] << 16);
        w2.y = (uint32_t)pk[2] | ((uint32_t)pk[3] << 16);
        *(uint2*)&Pw[li * 40 + itl * 16 + 4 * g] = w2;
      }
      short8 bP = ld8(&Pw[li * 40 + 8 * g]);
      #pragma unroll
      for (int ct = 0; ct < 4; ++ct) {
        short8 aV = ld8(&R3[cj_idx(ct * 16 + li, ip * 32 + 8 * g)]);
        acc[ct] = MFMA(aV, bP, acc[ct]);
      }
    }
    z += __shfl_xor(z, 16); z += __shfl_xor(z, 32);
    float invz = 1.0f / z;
    #pragma unroll
    for (int ct = 0; ct < 4; ++ct)
      #pragma unroll
      for (int r = 0; r < 4; ++r) {
        int c = ct * 16 + 4 * g + r;
        outR[(size_t)c * HW + pix] =
            fmaf(gamma3[c], acc[ct][r] * invz, xr[(size_t)c * HW + pix]);
      }
  }

  // ---------- pass 1: out_L column tile = own pixels; sum over j <= own ----------
  // (no barrier needed: R1/R2/R4 read-only since conv barrier, Pw wave-private)
  {
    short8 bQ0 = ld8(&R1[pc_idx(pix, g * 8)]);
    short8 bQ1 = ld8(&R1[pc_idx(pix, 32 + g * 8)]);
    f32x4 acc[4] = {{0,0,0,0},{0,0,0,0},{0,0,0,0},{0,0,0,0}};
    float z = 0.f;
    for (int jp = 0; jp <= h; ++jp) {
      #pragma unroll
      for (int itl = 0; itl < 2; ++itl) {
        int arow = jp * 32 + itl * 16 + li;
        short8 aS0 = ld8(&R2[pc_idx(arow, g * 8)]);
        short8 aS1 = ld8(&R2[pc_idx(arow, 32 + g * 8)]);
        f32x4 s = {0.f, 0.f, 0.f, 0.f};
        s = MFMA(aS0, bQ0, s);
        s = MFMA(aS1, bQ1, s);
        uint16_t pk[4];
        #pragma unroll
        for (int r = 0; r < 4; ++r) {
          int jidx = jp * 32 + itl * 16 + 4 * g + r;
          float p = (jidx <= pix) ? __expf(s[r]) : 0.f;
          z += p; pk[r] = bf16r(p);
        }
        uint2 w2;
        w2.x = (uint32_t)pk[0] | ((uint32_t)pk[1] << 16);
        w2.y = (uint32_t)pk[2] | ((uint32_t)pk[3] << 16);
        *(uint2*)&Pw[li * 40 + itl * 16 + 4 * g] = w2;
      }
      short8 bP = ld8(&Pw[li * 40 + 8 * g]);
      #pragma unroll
      for (int ct = 0; ct < 4; ++ct) {
        short8 aV = ld8(&R4[cj_idx(ct * 16 + li, jp * 32 + 8 * g)]);
        acc[ct] = MFMA(aV, bP, acc[ct]);
      }
    }
    z += __shfl_xor(z, 16); z += __shfl_xor(z, 32);
    float invz = 1.0f / z;
    #pragma unroll
    for (int ct = 0; ct < 4; ++ct)
      #pragma unroll
      for (int r = 0; r < 4; ++r) {
        int c = ct * 16 + 4 * g + r;
        outL[(size_t)c * HW + pix] =
            fmaf(beta3[c], acc[ct][r] * invz, xl[(size_t)c * HW + pix]);
      }
  }
}

extern "C" void kernel_launch(void* const* d_in, const int* in_sizes, int n_in,
                              void* d_out, int out_size, void* d_ws, size_t ws_size,
                              hipStream_t stream) {
  const float* x       = (const float*)d_in[0];
  const float* res_enc = (const float*)d_in[1];
  const float* tr_feat = (const float*)d_in[2];
  const float* Wl1     = (const float*)d_in[3];
  const float* bl1     = (const float*)d_in[4];
  const float* Wr1     = (const float*)d_in[5];
  const float* br1     = (const float*)d_in[6];
  const float* Wl2     = (const float*)d_in[7];
  const float* bl2     = (const float*)d_in[8];
  const float* Wr2     = (const float*)d_in[9];
  const float* br2     = (const float*)d_in[10];
  const float* beta1   = (const float*)d_in[11];
  const float* gamma1  = (const float*)d_in[12];
  const float* beta3   = (const float*)d_in[13];
  const float* gamma3  = (const float*)d_in[14];
  float* outp = (float*)d_out;

  dim3 grid(512);     // 2 left-batches x 256 rows
  dim3 block(1024);   // 16 waves, one 16-pixel column tile each
  SCAM_73151882985874_kernel<<<grid, block, 0, stream>>>(
      x, res_enc, tr_feat, Wl1, bl1, Wr1, br1, Wl2, bl2, Wr2, br2,
      beta1, gamma1, beta3, gamma3, outp);
}

// Round 4
// 92.603 us; speedup vs baseline: 1.1482x; 1.1482x over previous
//
#include <hip/hip_runtime.h>
#include <stdint.h>

#define HW 65536   // 256*256
#define C_ 64

typedef __attribute__((ext_vector_type(8))) short short8;
typedef __attribute__((ext_vector_type(4))) float f32x4;

#define MFMA(a, b, c) __builtin_amdgcn_mfma_f32_16x16x32_bf16((a), (b), (c), 0, 0, 0)

union U16x8 { uint4 q; short8 v; uint32_t u[4]; };

__device__ inline uint32_t pack_bf16(float lo, float hi) {
  uint32_t ul = __float_as_uint(lo), uh = __float_as_uint(hi);
  ul = (ul + 0x7fffu + ((ul >> 16) & 1u)) >> 16;
  uh = (uh + 0x7fffu + ((uh >> 16) & 1u)) >> 16;
  return ul | (uh << 16);
}
__device__ inline uint16_t bf16r(float f) {
  uint32_t u = __float_as_uint(f);
  return (uint16_t)((u + 0x7fffu + ((u >> 16) & 1u)) >> 16);
}
__device__ inline short8 ld8(const uint16_t* p) {
  U16x8 t; t.q = *(const uint4*)p; return t.v;
}
// [pixel][64 c] bf16 tile, XOR swizzle (16B granule)
__device__ inline int pc_idx(int pixel, int c) {
  return (pixel * 64 + c) ^ ((pixel & 7) << 3);
}
// [c][256 j] bf16 tile (V layout)
__device__ inline int cj_idx(int c, int j) {
  return (c * 256 + j) ^ ((c & 7) << 3);
}

// ---- pre-kernel: pack the 64x64 cores of the 4 weight matrices to bf16 in d_ws
__global__ void SCAM_pack_w(const float* __restrict__ Wl1, const float* __restrict__ Wr1,
                            const float* __restrict__ Wl2, const float* __restrict__ Wr2,
                            uint16_t* __restrict__ ws) {
  int idx = blockIdx.x * 256 + threadIdx.x;   // 16 blocks x 256 = 4096 = 64x64
  int r = idx >> 6, k = idx & 63;
  ws[idx]         = bf16r(Wl1[r * 66 + k]);
  ws[4096 + idx]  = bf16r(Wr1[r * 66 + k]);
  ws[8192 + idx]  = bf16r(Wl2[r * 64 + k]);
  ws[12288 + idx] = bf16r(Wr2[r * 64 + k]);
}

__global__ __launch_bounds__(512, 2) void SCAM_73151882985874_kernel(
    const float* __restrict__ x, const float* __restrict__ res_enc,
    const float* __restrict__ tr_feat,
    const float* __restrict__ Wl1, const float* __restrict__ bl1,
    const float* __restrict__ Wr1, const float* __restrict__ br1,
    const float* __restrict__ Wl2, const float* __restrict__ bl2,
    const float* __restrict__ Wr2, const float* __restrict__ br2,
    const float* __restrict__ beta1, const float* __restrict__ gamma1,
    const float* __restrict__ beta3, const float* __restrict__ gamma3,
    const uint16_t* __restrict__ wsW,
    float* __restrict__ out)
{
  __shared__ uint16_t R1[16384];   // xl -> Q*0.125 (in-place)  [pixel][c]
  __shared__ uint16_t R2[16384];   // xr -> S       (in-place)  [pixel][c]
  __shared__ uint16_t R3[16384];   // bufL   [c][j]
  __shared__ uint16_t R4[16384];   // bufR   [c][j]
  __shared__ uint16_t sP[10240];   // per-wave P: 8 x [16 cols x2][40]

  const int tid = threadIdx.x;
  const int wid = tid >> 6, lane = tid & 63, g = lane >> 4, li = lane & 15;
  const int bb = blockIdx.x >> 8, hh = blockIdx.x & 255;
  const float yy = (float)hh * (2.0f / 255.0f) - 1.0f;
  const float rr = fabsf(yy - 0.5f);

  const size_t rowoff = (size_t)hh * 256;
  const float* xl  = x + ((size_t)bb * C_) * HW + rowoff;
  const float* xr  = x + ((size_t)(2 + bb) * C_) * HW + rowoff;
  const float* trl = tr_feat + ((size_t)bb * C_) * HW + rowoff;
  const float* trr = tr_feat + ((size_t)(2 + bb) * C_) * HW + rowoff;
  const float* rel = res_enc + ((size_t)bb * C_) * HW + rowoff;
  const float* rer = res_enc + ((size_t)(2 + bb) * C_) * HW + rowoff;
  float* outL = out + ((size_t)bb * C_) * HW + rowoff;
  float* outR = out + ((size_t)(2 + bb) * C_) * HW + rowoff;

  // ---------- Phase A: stage xl -> R1, xr -> R2 (f32 -> bf16 [pixel][c]) ----------
  {
    const int side = tid >> 8;         // 0: left, 1: right
    const int p    = tid & 255;
    const float* src = side ? xr : xl;
    uint16_t* dst = side ? R2 : R1;
    #pragma unroll
    for (int cb = 0; cb < 8; ++cb) {
      int c0 = cb * 8;
      const float* s = src + (size_t)c0 * HW + p;
      U16x8 t8;
      t8.u[0] = pack_bf16(s[0],              s[(size_t)HW]);
      t8.u[1] = pack_bf16(s[2 * (size_t)HW], s[3 * (size_t)HW]);
      t8.u[2] = pack_bf16(s[4 * (size_t)HW], s[5 * (size_t)HW]);
      t8.u[3] = pack_bf16(s[6 * (size_t)HW], s[7 * (size_t)HW]);
      *(uint4*)&dst[pc_idx(p, c0)] = t8.q;
    }
  }
  __syncthreads();

  // x fragments for this wave's 32 pixels, into regs BEFORE in-place overwrite
  short8 bxL[2][2], bxR[2][2];
  #pragma unroll
  for (int ptl = 0; ptl < 2; ++ptl) {
    int pix = wid * 32 + ptl * 16 + li;
    bxL[ptl][0] = ld8(&R1[pc_idx(pix, g * 8)]);
    bxL[ptl][1] = ld8(&R1[pc_idx(pix, 32 + g * 8)]);
    bxR[ptl][0] = ld8(&R2[pc_idx(pix, g * 8)]);
    bxR[ptl][1] = ld8(&R2[pc_idx(pix, 32 + g * 8)]);
  }

  // ---------- Phase B: all four 1x1 convs (MFMA), one barrier after ----------
  auto conv_one = [&](const uint16_t* __restrict__ wcore,
                      const float* __restrict__ Wc,  // coord cols (f32, stride 66) or null
                      const float* __restrict__ bias, const float* __restrict__ mod,
                      const float* __restrict__ E, float qscale,
                      const short8 bx[2][2], uint16_t* dstPC, uint16_t* dstV) {
    // W fragments: direct bf16 16B loads (L2-resident after first blocks)
    short8 af[4][2];
    #pragma unroll
    for (int ct = 0; ct < 4; ++ct) {
      const uint16_t* wr = wcore + (size_t)(ct * 16 + li) * 64 + g * 8;
      af[ct][0] = ld8(wr);
      af[ct][1] = ld8(wr + 32);
    }
    // effective bias + modulation, hoisted over ptl
    float be[4][4], md[4][4];
    #pragma unroll
    for (int ct = 0; ct < 4; ++ct)
      #pragma unroll
      for (int r = 0; r < 4; ++r) {
        int c = ct * 16 + 4 * g + r;
        float b = bias[c];
        if (Wc) b += Wc[(size_t)c * 66 + 64] * yy + Wc[(size_t)c * 66 + 65] * rr;
        be[ct][r] = b;
        md[ct][r] = mod[c];
      }
    #pragma unroll
    for (int ptl = 0; ptl < 2; ++ptl) {
      int pix = wid * 32 + ptl * 16 + li;
      #pragma unroll
      for (int ct = 0; ct < 4; ++ct) {
        float ev[4];
        #pragma unroll
        for (int r = 0; r < 4; ++r)
          ev[r] = E[(size_t)(ct * 16 + 4 * g + r) * HW + pix];
        f32x4 acc = {0.f, 0.f, 0.f, 0.f};
        acc = MFMA(af[ct][0], bx[ptl][0], acc);
        acc = MFMA(af[ct][1], bx[ptl][1], acc);
        uint16_t pk[4];
        #pragma unroll
        for (int r = 0; r < 4; ++r)
          pk[r] = bf16r((acc[r] + be[ct][r] + md[ct][r] * ev[r]) * qscale);
        if (dstV) {
          #pragma unroll
          for (int r = 0; r < 4; ++r) dstV[cj_idx(ct * 16 + 4 * g + r, pix)] = pk[r];
        } else {
          uint2 w2;
          w2.x = (uint32_t)pk[0] | ((uint32_t)pk[1] << 16);
          w2.y = (uint32_t)pk[2] | ((uint32_t)pk[3] << 16);
          *(uint2*)&dstPC[pc_idx(pix, ct * 16 + 4 * g)] = w2;
        }
      }
    }
  };

  conv_one(wsW,         Wl1, bl1, beta1,  trl, 0.125f, bxL, R1, nullptr);  // Q (scaled)
  conv_one(wsW + 4096,  Wr1, br1, beta1,  trr, 1.0f,   bxR, R2, nullptr);  // S
  conv_one(wsW + 8192,  nullptr, bl2, gamma1, rel, 1.0f, bxL, nullptr, R3); // bufL
  conv_one(wsW + 12288, nullptr, br2, gamma1, rer, 1.0f, bxR, nullptr, R4); // bufR
  __syncthreads();

  uint16_t* Pw = &sP[wid * 1280];
  const int j0 = wid * 32;

  // ---------- pass 2: out_R cols = own 32 pixels; sum over a >= col ----------
  {
    short8 bS[2][2];
    #pragma unroll
    for (int jt = 0; jt < 2; ++jt) {
      bS[jt][0] = ld8(&R2[pc_idx(j0 + jt * 16 + li, g * 8)]);
      bS[jt][1] = ld8(&R2[pc_idx(j0 + jt * 16 + li, 32 + g * 8)]);
    }
    f32x4 acc[4][2];
    #pragma unroll
    for (int ct = 0; ct < 4; ++ct) { acc[ct][0] = (f32x4){0,0,0,0}; acc[ct][1] = (f32x4){0,0,0,0}; }
    float zp0 = 0.f, zp1 = 0.f;

    for (int ip = wid; ip < 8; ++ip) {
      short8 aQ[2][2];
      #pragma unroll
      for (int itl = 0; itl < 2; ++itl) {
        int arow = ip * 32 + itl * 16 + li;
        aQ[itl][0] = ld8(&R1[pc_idx(arow, g * 8)]);
        aQ[itl][1] = ld8(&R1[pc_idx(arow, 32 + g * 8)]);
      }
      #pragma unroll
      for (int itl = 0; itl < 2; ++itl)
        #pragma unroll
        for (int jt = 0; jt < 2; ++jt) {
          f32x4 s = {0.f, 0.f, 0.f, 0.f};
          s = MFMA(aQ[itl][0], bS[jt][0], s);
          s = MFMA(aQ[itl][1], bS[jt][1], s);
          int jj = j0 + jt * 16 + li;
          float ps = 0.f; uint16_t pk[4];
          #pragma unroll
          for (int r = 0; r < 4; ++r) {
            int aidx = ip * 32 + itl * 16 + 4 * g + r;
            float p = (aidx >= jj) ? __expf(s[r]) : 0.f;
            ps += p; pk[r] = bf16r(p);
          }
          if (jt == 0) zp0 += ps; else zp1 += ps;
          uint2 w2;
          w2.x = (uint32_t)pk[0] | ((uint32_t)pk[1] << 16);
          w2.y = (uint32_t)pk[2] | ((uint32_t)pk[3] << 16);
          *(uint2*)&Pw[(jt * 16 + li) * 40 + itl * 16 + 4 * g] = w2;
        }
      short8 aV[4];
      #pragma unroll
      for (int ct = 0; ct < 4; ++ct)
        aV[ct] = ld8(&R3[cj_idx(ct * 16 + li, ip * 32 + 8 * g)]);
      #pragma unroll
      for (int jt = 0; jt < 2; ++jt) {
        short8 bP = ld8(&Pw[(jt * 16 + li) * 40 + 8 * g]);
        #pragma unroll
        for (int ct = 0; ct < 4; ++ct)
          acc[ct][jt] = MFMA(aV[ct], bP, acc[ct][jt]);
      }
    }
    zp0 += __shfl_xor(zp0, 16); zp0 += __shfl_xor(zp0, 32);
    zp1 += __shfl_xor(zp1, 16); zp1 += __shfl_xor(zp1, 32);
    #pragma unroll
    for (int jt = 0; jt < 2; ++jt) {
      float invz = 1.0f / (jt == 0 ? zp0 : zp1);
      int j = j0 + jt * 16 + li;
      #pragma unroll
      for (int ct = 0; ct < 4; ++ct)
        #pragma unroll
        for (int r = 0; r < 4; ++r) {
          int c = ct * 16 + 4 * g + r;
          outR[(size_t)c * HW + j] =
              fmaf(gamma3[c], acc[ct][jt][r] * invz, xr[(size_t)c * HW + j]);
        }
    }
  }

  // ---------- pass 1: out_L cols = own 32 pixels; sum over j <= col ----------
  // (no barrier: R1/R2/R4 read-only since conv barrier; Pw wave-private)
  {
    short8 bQ[2][2];
    #pragma unroll
    for (int itl = 0; itl < 2; ++itl) {
      bQ[itl][0] = ld8(&R1[pc_idx(j0 + itl * 16 + li, g * 8)]);
      bQ[itl][1] = ld8(&R1[pc_idx(j0 + itl * 16 + li, 32 + g * 8)]);
    }
    f32x4 acc[4][2];
    #pragma unroll
    for (int ct = 0; ct < 4; ++ct) { acc[ct][0] = (f32x4){0,0,0,0}; acc[ct][1] = (f32x4){0,0,0,0}; }
    float zp0 = 0.f, zp1 = 0.f;

    for (int jp = 0; jp <= wid; ++jp) {
      short8 aS[2][2];
      #pragma unroll
      for (int jtl = 0; jtl < 2; ++jtl) {
        int arow = jp * 32 + jtl * 16 + li;
        aS[jtl][0] = ld8(&R2[pc_idx(arow, g * 8)]);
        aS[jtl][1] = ld8(&R2[pc_idx(arow, 32 + g * 8)]);
      }
      #pragma unroll
      for (int jtl = 0; jtl < 2; ++jtl)
        #pragma unroll
        for (int itl = 0; itl < 2; ++itl) {
          f32x4 s = {0.f, 0.f, 0.f, 0.f};
          s = MFMA(aS[jtl][0], bQ[itl][0], s);
          s = MFMA(aS[jtl][1], bQ[itl][1], s);
          int ii = j0 + itl * 16 + li;
          float ps = 0.f; uint16_t pk[4];
          #pragma unroll
          for (int r = 0; r < 4; ++r) {
            int jidx = jp * 32 + jtl * 16 + 4 * g + r;
            float p = (jidx <= ii) ? __expf(s[r]) : 0.f;
            ps += p; pk[r] = bf16r(p);
          }
          if (itl == 0) zp0 += ps; else zp1 += ps;
          uint2 w2;
          w2.x = (uint32_t)pk[0] | ((uint32_t)pk[1] << 16);
          w2.y = (uint32_t)pk[2] | ((uint32_t)pk[3] << 16);
          *(uint2*)&Pw[(itl * 16 + li) * 40 + jtl * 16 + 4 * g] = w2;
        }
      short8 aV[4];
      #pragma unroll
      for (int ct = 0; ct < 4; ++ct)
        aV[ct] = ld8(&R4[cj_idx(ct * 16 + li, jp * 32 + 8 * g)]);
      #pragma unroll
      for (int itl = 0; itl < 2; ++itl) {
        short8 bP = ld8(&Pw[(itl * 16 + li) * 40 + 8 * g]);
        #pragma unroll
        for (int ct = 0; ct < 4; ++ct)
          acc[ct][itl] = MFMA(aV[ct], bP, acc[ct][itl]);
      }
    }
    zp0 += __shfl_xor(zp0, 16); zp0 += __shfl_xor(zp0, 32);
    zp1 += __shfl_xor(zp1, 16); zp1 += __shfl_xor(zp1, 32);
    #pragma unroll
    for (int itl = 0; itl < 2; ++itl) {
      float invz = 1.0f / (itl == 0 ? zp0 : zp1);
      int i = j0 + itl * 16 + li;
      #pragma unroll
      for (int ct = 0; ct < 4; ++ct)
        #pragma unroll
        for (int r = 0; r < 4; ++r) {
          int c = ct * 16 + 4 * g + r;
          outL[(size_t)c * HW + i] =
              fmaf(beta3[c], acc[ct][itl][r] * invz, xl[(size_t)c * HW + i]);
        }
    }
  }
}

extern "C" void kernel_launch(void* const* d_in, const int* in_sizes, int n_in,
                              void* d_out, int out_size, void* d_ws, size_t ws_size,
                              hipStream_t stream) {
  const float* x       = (const float*)d_in[0];
  const float* res_enc = (const float*)d_in[1];
  const float* tr_feat = (const float*)d_in[2];
  const float* Wl1     = (const float*)d_in[3];
  const float* bl1     = (const float*)d_in[4];
  const float* Wr1     = (const float*)d_in[5];
  const float* br1     = (const float*)d_in[6];
  const float* Wl2     = (const float*)d_in[7];
  const float* bl2     = (const float*)d_in[8];
  const float* Wr2     = (const float*)d_in[9];
  const float* br2     = (const float*)d_in[10];
  const float* beta1   = (const float*)d_in[11];
  const float* gamma1  = (const float*)d_in[12];
  const float* beta3   = (const float*)d_in[13];
  const float* gamma3  = (const float*)d_in[14];
  float* outp = (float*)d_out;
  uint16_t* wsW = (uint16_t*)d_ws;   // 16384 u16 = 32 KB

  SCAM_pack_w<<<dim3(16), dim3(256), 0, stream>>>(Wl1, Wr1, Wl2, Wr2, wsW);

  dim3 grid(512);    // 2 left-batches x 256 rows
  dim3 block(512);   // 8 waves, one 32-pixel column tile each
  SCAM_73151882985874_kernel<<<grid, block, 0, stream>>>(
      x, res_enc, tr_feat, Wl1, bl1, Wr1, br1, Wl2, bl2, Wr2, br2,
      beta1, gamma1, beta3, gamma3, wsW, outp);
}